// Round 10
// baseline (702.262 us; speedup 1.0000x reference)
//
#include <hip/hip_runtime.h>

typedef _Float16 f16x8 __attribute__((ext_vector_type(8)));
typedef _Float16 f16x4 __attribute__((ext_vector_type(4)));
typedef float f32x4 __attribute__((ext_vector_type(4)));

static __device__ __forceinline__ f32x4 MFMA(f16x8 a, f16x8 b, f32x4 c) {
  return __builtin_amdgcn_mfma_f32_16x16x32_f16(a, b, c, 0, 0, 0);
}

// ---- weight conversion pre-kernel ------------------------------------------
// ws layout:
//   Wb   : 3 x [224][256] f16  (Wq,Wk,Wv; rows >=200 zero)      @ 0       (344064 B)
//   Wcb  : [224][1024] f16     (conv_w flat; rows >=200 zero)   @ 344064  (458752 B)
//   biasp: 3 x [224] f32       (bq,bk,bv padded w/ zeros)       @ 802816  (2688 B)
__global__ void wcvt(const float* __restrict__ Wq, const float* __restrict__ Wk,
                     const float* __restrict__ Wv, const float* __restrict__ cw,
                     const float* __restrict__ bq, const float* __restrict__ bk,
                     const float* __restrict__ bv,
                     _Float16* __restrict__ Wb,
                     _Float16* __restrict__ Wcb,
                     float* __restrict__ biasp) {
  int gt = blockIdx.x * blockDim.x + threadIdx.x;
  int gs = gridDim.x * blockDim.x;
  const int WN = 224 * 256;
  for (int i = gt; i < WN; i += gs) {
    int n = i >> 8;
    Wb[i]          = (n < 200) ? (_Float16)Wq[i] : (_Float16)0.f;
    Wb[WN + i]     = (n < 200) ? (_Float16)Wk[i] : (_Float16)0.f;
    Wb[2 * WN + i] = (n < 200) ? (_Float16)Wv[i] : (_Float16)0.f;
  }
  for (int i = gt; i < 224 * 1024; i += gs) {
    int o = i >> 10;
    Wcb[i] = (o < 200) ? (_Float16)cw[i] : (_Float16)0.f;
  }
  for (int i = gt; i < 224; i += gs) {
    biasp[i]       = (i < 200) ? bq[i] : 0.f;
    biasp[224 + i] = (i < 200) ? bk[i] : 0.f;
    biasp[448 + i] = (i < 200) ? bv[i] : 0.f;
  }
}

// ---- fused kernel: 1024 threads (16 waves), 1 batch/block -------------------
// LDS map (bytes):
//   Xl [64][264] f16 @ 0       (33792)
//   Qs [64][232] f16 @ 33792   (29696)   [l][n]
//   Ks [64][232] f16 @ 63488   (29696)   [l][n]
//   Vt [224][64] f16 @ 93184   (28672)   [h][m], xor-swizzled m-chunks
//   Sf [64][65]  f32 @ 121856  (16640)   scores
//   Sb [64][72]  f16 @ 138496  (9216)    softmaxed P
//   Po [200][17] f32 @ 147712  (13600)   conv+bias, then += pooled att
// total 161312 <= 163840
#define FU_LDS 161312

__global__ __launch_bounds__(1024, 4) void fused_all(
    const float* __restrict__ x, const _Float16* __restrict__ Wb,
    const _Float16* __restrict__ Wcb, const float* __restrict__ biasp,
    const float* __restrict__ convb, float* __restrict__ out) {
  extern __shared__ char smem[];
  _Float16* Xl = (_Float16*)smem;             // [64][264]
  _Float16* Qs = (_Float16*)(smem + 33792);   // [64][232]
  _Float16* Ks = (_Float16*)(smem + 63488);   // [64][232]
  _Float16* Vt = (_Float16*)(smem + 93184);   // [224][64] swizzled
  float*    Sf = (float*)(smem + 121856);     // [64][65]
  _Float16* Sb = (_Float16*)(smem + 138496);  // [64][72]
  float*    Po = (float*)(smem + 147712);     // [200][17]

  const int b = blockIdx.x;
  const int tid = threadIdx.x;
  const int lane = tid & 63;
  const int wave = tid >> 6;     // 0..15
  const int li = lane & 15;
  const int g = lane >> 4;

  // ---- Phase A: x -> f16 Xl (coalesced float4) ----
  const float* xb = x + (size_t)b * 16384;
#pragma unroll
  for (int j = 0; j < 4; j++) {
    int f = tid + 1024 * j;          // float4 index 0..4095
    float4 v = ((const float4*)xb)[f];
    int l = f >> 6, c4 = f & 63;
    f16x4 h;
    h.x = (_Float16)v.x; h.y = (_Float16)v.y;
    h.z = (_Float16)v.z; h.w = (_Float16)v.w;
    *(f16x4*)(Xl + l * 264 + c4 * 4) = h;
  }
  __syncthreads();

  // ---- Phase B: 56 units over 16 waves: Q(0..13) K(14..27) V(28..41) conv(42..55)
#pragma unroll 1
  for (int u = wave; u < 56; u += 16) {
    if (u < 28) {
      // Q/K: swapped operands -> D[n][l]; vectorized LDS store along n
      int p = u / 14, nt = u % 14;
      const _Float16* wrow = Wb + p * 57344 + (nt * 16 + li) * 256 + 8 * g;
      _Float16* dst = (p == 0) ? Qs : Ks;
      f32x4 acc[4] = {};
#pragma unroll
      for (int kk = 0; kk < 8; kk++) {
        f16x8 aw = *(const f16x8*)(wrow + 32 * kk);
#pragma unroll
        for (int mt = 0; mt < 4; mt++) {
          f16x8 bx = *(const f16x8*)(Xl + (mt * 16 + li) * 264 + 32 * kk + 8 * g);
          acc[mt] = MFMA(aw, bx, acc[mt]);
        }
      }
      float4 b4 = *(const float4*)(biasp + p * 224 + nt * 16 + 4 * g);
#pragma unroll
      for (int mt = 0; mt < 4; mt++) {
        f16x4 hv;
        float v0 = acc[mt][0] + b4.x; hv[0] = (_Float16)(v0 > 0.f ? v0 : 0.f);
        float v1 = acc[mt][1] + b4.y; hv[1] = (_Float16)(v1 > 0.f ? v1 : 0.f);
        float v2 = acc[mt][2] + b4.z; hv[2] = (_Float16)(v2 > 0.f ? v2 : 0.f);
        float v3 = acc[mt][3] + b4.w; hv[3] = (_Float16)(v3 > 0.f ? v3 : 0.f);
        *(f16x4*)(dst + (mt * 16 + li) * 232 + nt * 16 + 4 * g) = hv;
      }
    } else if (u < 42) {
      // V: normal operands -> D[m][h]; store Vt[h][m] swizzled, f16x4 along m
      int nt = u - 28;
      const _Float16* wrow = Wb + 2 * 57344 + (nt * 16 + li) * 256 + 8 * g;
      f32x4 acc[4] = {};
#pragma unroll
      for (int kk = 0; kk < 8; kk++) {
        f16x8 bw = *(const f16x8*)(wrow + 32 * kk);
#pragma unroll
        for (int mt = 0; mt < 4; mt++) {
          f16x8 ax = *(const f16x8*)(Xl + (mt * 16 + li) * 264 + 32 * kk + 8 * g);
          acc[mt] = MFMA(ax, bw, acc[mt]);
        }
      }
      float bias = biasp[448 + nt * 16 + li];
      int h = nt * 16 + li;
#pragma unroll
      for (int mt = 0; mt < 4; mt++) {
        f16x4 hv;
#pragma unroll
        for (int r = 0; r < 4; r++) {
          float v = acc[mt][r] + bias;
          hv[r] = (_Float16)(v > 0.f ? v : 0.f);
        }
        int c = mt * 2 + (g >> 1);           // m-chunk (8 f16)
        int sub = (g & 1) * 4;
        *(f16x4*)(Vt + h * 64 + ((c ^ (h & 7)) << 3) + sub) = hv;
      }
    } else {
      // conv unit: [16 x 1024] * [1024 x 224] -> Po (with bias)
      int nt = u - 42, o = nt * 16 + li;
      const _Float16* wrow = Wcb + o * 1024 + 8 * g;
      f32x4 acc = {};
#pragma unroll 4
      for (int kk = 0; kk < 32; kk++) {
        int i1 = kk * 8 + 2 * g;
        int i2 = i1 + 1;
        union { f16x4 h[2]; f16x8 v; } af;
        af.h[0] = *(const f16x4*)(Xl + (i1 >> 2) * 264 + ((i1 & 3) << 6) + 4 * li);
        af.h[1] = *(const f16x4*)(Xl + (i2 >> 2) * 264 + ((i2 & 3) << 6) + 4 * li);
        acc = MFMA(af.v, *(const f16x8*)(wrow + 32 * kk), acc);
      }
      if (o < 200) {
        float cb = convb[o];
#pragma unroll
        for (int r = 0; r < 4; r++) Po[o * 17 + 4 * g + r] = acc[r] + cb;
      }
    }
  }
  __syncthreads();

  // ---- Phase C: scores — one 16x16 tile per wave ----
  {
    int mt = wave >> 2, nt = wave & 3;
    f32x4 sacc = {};
#pragma unroll
    for (int kk = 0; kk < 7; kk++) {
      f16x8 qa = *(const f16x8*)(Qs + (mt * 16 + li) * 232 + kk * 32 + 8 * g);
      f16x8 kb = *(const f16x8*)(Ks + (nt * 16 + li) * 232 + kk * 32 + 8 * g);
      sacc = MFMA(qa, kb, sacc);
    }
#pragma unroll
    for (int r = 0; r < 4; r++)
      Sf[(mt * 16 + 4 * g + r) * 65 + nt * 16 + li] = sacc[r];
  }
  __syncthreads();

  // ---- Phase D: column softmax (dim=1, over rows l); 16 threads per column --
  {
    int m = tid >> 4, r16 = tid & 15;
    float vals[4], mx = -1e30f;
#pragma unroll
    for (int i = 0; i < 4; i++) {
      float v = Sf[(r16 + 16 * i) * 65 + m];
      vals[i] = v; mx = fmaxf(mx, v);
    }
    mx = fmaxf(mx, __shfl_xor(mx, 1));
    mx = fmaxf(mx, __shfl_xor(mx, 2));
    mx = fmaxf(mx, __shfl_xor(mx, 4));
    mx = fmaxf(mx, __shfl_xor(mx, 8));
    float s = 0.f;
#pragma unroll
    for (int i = 0; i < 4; i++) { vals[i] = __expf(vals[i] - mx); s += vals[i]; }
    s += __shfl_xor(s, 1);
    s += __shfl_xor(s, 2);
    s += __shfl_xor(s, 4);
    s += __shfl_xor(s, 8);
    float inv = 1.f / s;
#pragma unroll
    for (int i = 0; i < 4; i++)
      Sb[(r16 + 16 * i) * 72 + m] = (_Float16)(vals[i] * inv);
  }
  __syncthreads();

  // ---- Phase E: PV + pooled atomics into Po (14 units over 16 waves) ----
  if (wave < 14) {
    int ntl = wave;
    int h = ntl * 16 + li;
    f16x8 pa[2][4];
#pragma unroll
    for (int kk = 0; kk < 2; kk++)
#pragma unroll
      for (int m2 = 0; m2 < 4; m2++)
        pa[kk][m2] = *(const f16x8*)(Sb + (m2 * 16 + li) * 72 + kk * 32 + 8 * g);
    f16x8 vb[2];
#pragma unroll
    for (int kk = 0; kk < 2; kk++) {
      int cm = kk * 4 + g;
      vb[kk] = *(const f16x8*)(Vt + h * 64 + ((cm ^ (h & 7)) << 3));
    }
    f32x4 pacc[4] = {};
#pragma unroll
    for (int kk = 0; kk < 2; kk++)
#pragma unroll
      for (int m2 = 0; m2 < 4; m2++)
        pacc[m2] = MFMA(pa[kk][m2], vb[kk], pacc[m2]);
    if (h < 200) {
#pragma unroll
      for (int m2 = 0; m2 < 4; m2++)
#pragma unroll
        for (int r = 0; r < 4; r++) {
          int l = m2 * 16 + 4 * g + r;
          int f = l * 200 + h;
          atomicAdd(&Po[(f >> 6) * 17 + (f & 15)], 0.25f * pacc[m2][r]);
        }
    }
  }
  __syncthreads();

  // ---- Phase F: single out write ----
  float* ob = out + (size_t)b * 3200;
#pragma unroll 1
  for (int t = tid; t < 3200; t += 1024)
    ob[t] = Po[(t >> 4) * 17 + (t & 15)];
}

// ---- launch -----------------------------------------------------------------
extern "C" void kernel_launch(void* const* d_in, const int* in_sizes, int n_in,
                              void* d_out, int out_size, void* d_ws, size_t ws_size,
                              hipStream_t stream) {
  const float* x  = (const float*)d_in[0];
  const float* Wq = (const float*)d_in[1];
  const float* bq = (const float*)d_in[2];
  const float* Wk = (const float*)d_in[3];
  const float* bk = (const float*)d_in[4];
  const float* Wv = (const float*)d_in[5];
  const float* bv = (const float*)d_in[6];
  const float* cw = (const float*)d_in[7];
  const float* cb = (const float*)d_in[8];

  char* ws = (char*)d_ws;
  _Float16* Wb  = (_Float16*)ws;             // 344064 B
  _Float16* Wcb = (_Float16*)(ws + 344064);  // 458752 B
  float* biasp  = (float*)(ws + 802816);     // 2688 B

  hipLaunchKernelGGL(wcvt, dim3(512), dim3(256), 0, stream,
                     Wq, Wk, Wv, cw, bq, bk, bv, Wb, Wcb, biasp);

  hipFuncSetAttribute((const void*)fused_all,
                      hipFuncAttributeMaxDynamicSharedMemorySize, FU_LDS);
  hipLaunchKernelGGL(fused_all, dim3(4096), dim3(1024), FU_LDS, stream,
                     x, Wb, Wcb, biasp, cb, (float*)d_out);
}